// Round 2
// baseline (171.075 us; speedup 1.0000x reference)
//
#include <hip/hip_runtime.h>

// All tensors float32. Output = concat(vec[3E], dist[E], switch[E], mask[E]).
//
// R1 post-mortem: 71us, HBM 20%, VALU 8% -> bound by divergent-gather lane
// throughput (6 scalar dword gathers/edge, 12B payload straddling lines).
// R2: pack coords into float4[N] in d_ws (prepass) so each node gather is a
// single 16B-aligned dwordx4 (one line, one instr).
// R3 theory: ~141 MB of read-once/write-once streaming traffic thrashes the
// 4 MiB/XCD L2, evicting the 1.6 MB packed coord table -> every gather is an
// L2 miss (L3/HBM latency + line over-fetch). Fix: nt-flagged loads for the
// streaming inputs and nt-flagged stores for all outputs so the coord table
// stays L2-resident; gathers stay normally cached. Arithmetic unchanged
// (must stay bit-exact: the d<5 mask is a cliff; fp contract OFF, numpy op
// order, OCML sqrtf).
// R4: resubmit of R3 unchanged — both prior rounds died in infra
// (GPU acquisition / container failure) with no counters; no evidence
// against the R3 theory, and stacking unmeasured edits breaks attribution.

typedef float f32x4 __attribute__((ext_vector_type(4)));
typedef int   i32x4 __attribute__((ext_vector_type(4)));

__device__ __forceinline__ void edge_math(
    float dx0, float dx1, float dx2,
    float sh0, float sh1, float sh2, const float c[9],
    float& v0, float& v1, float& v2, float& dist, float& sw, float& mk)
{
#pragma clang fp contract(off)
    float m0 = sh0 * c[0]; m0 = m0 + sh1 * c[3]; m0 = m0 + sh2 * c[6];
    float m1 = sh0 * c[1]; m1 = m1 + sh1 * c[4]; m1 = m1 + sh2 * c[7];
    float m2 = sh0 * c[2]; m2 = m2 + sh1 * c[5]; m2 = m2 + sh2 * c[8];
    v0 = dx0 + m0; v1 = dx1 + m1; v2 = dx2 + m2;
    float q = v0 * v0; q = q + v1 * v1; q = q + v2 * v2;
    dist = sqrtf(q);
    bool m = dist < 5.0f;
    float cv = cosf(dist * 0.62831853f);   // f32(pi/5)
    sw = m ? (0.5f * cv + 0.5f) : 0.0f;
    mk = m ? 1.0f : 0.0f;
}

// ---- prepass: coords[N,3] -> packed float4[N] in ws ----
// packed table is the one thing we WANT in L2 -> regular (caching) stores.
__global__ __launch_bounds__(256) void pack_coords_kernel(
    const float* __restrict__ coords, float4* __restrict__ packed, int n_nodes)
{
    int i = blockIdx.x * blockDim.x + threadIdx.x;
    if (i >= n_nodes) return;
    const float* p = coords + 3 * (size_t)i;
    packed[i] = make_float4(p[0], p[1], p[2], 0.0f);
}

// ---- main kernel, packed-float4 gather path, nt streaming ----
__global__ __launch_bounds__(256) void GraphProcessor_64012192579962_kernel(
    const float4* __restrict__ packed,  // [N] xyz_
    const int*   __restrict__ esrc,     // [E]
    const int*   __restrict__ edst,     // [E]
    const float* __restrict__ shifts,   // [E,3]
    const float* __restrict__ cells,    // [9]
    float* __restrict__ out_vec,        // [E,3]
    float* __restrict__ out_dist,       // [E]
    float* __restrict__ out_sw,         // [E]
    float* __restrict__ out_mask,       // [E]
    int n_quads, int n_edges)
{
#pragma clang fp contract(off)
    int t = blockIdx.x * blockDim.x + threadIdx.x;
    if (t >= n_quads) return;

    float c[9];
#pragma unroll
    for (int i = 0; i < 9; ++i) c[i] = cells[i];   // uniform -> scalar loads

    const int e0 = 4 * t;

    if (e0 + 3 < n_edges) {
        // streaming, read-once -> nontemporal (don't evict the coord table)
        i32x4 ss = __builtin_nontemporal_load((const i32x4*)esrc + t);
        i32x4 dd = __builtin_nontemporal_load((const i32x4*)edst + t);
        const f32x4* shp = (const f32x4*)(shifts + 12 * (size_t)t);
        f32x4 h0 = __builtin_nontemporal_load(shp + 0);
        f32x4 h1 = __builtin_nontemporal_load(shp + 1);
        f32x4 h2 = __builtin_nontemporal_load(shp + 2);

        // issue all 8 gathers before any compute (max outstanding loads).
        // gathers stay normally cached: 1.6 MB table should be L2-resident.
        float4 s0 = packed[ss.x], s1 = packed[ss.y], s2 = packed[ss.z], s3 = packed[ss.w];
        float4 d0 = packed[dd.x], d1 = packed[dd.y], d2 = packed[dd.z], d3 = packed[dd.w];

        float v[12], di[4], sw[4], mk[4];
        edge_math(d0.x - s0.x, d0.y - s0.y, d0.z - s0.z, h0.x, h0.y, h0.z, c, v[0], v[1],  v[2],  di[0], sw[0], mk[0]);
        edge_math(d1.x - s1.x, d1.y - s1.y, d1.z - s1.z, h0.w, h1.x, h1.y, c, v[3], v[4],  v[5],  di[1], sw[1], mk[1]);
        edge_math(d2.x - s2.x, d2.y - s2.y, d2.z - s2.z, h1.z, h1.w, h2.x, c, v[6], v[7],  v[8],  di[2], sw[2], mk[2]);
        edge_math(d3.x - s3.x, d3.y - s3.y, d3.z - s3.z, h2.y, h2.z, h2.w, c, v[9], v[10], v[11], di[3], sw[3], mk[3]);

        // write-once outputs -> nontemporal stores (no write-allocate thrash)
        f32x4* ov = (f32x4*)(out_vec + 12 * (size_t)t);
        f32x4 o0 = { v[0], v[1], v[2],  v[3]  };
        f32x4 o1 = { v[4], v[5], v[6],  v[7]  };
        f32x4 o2 = { v[8], v[9], v[10], v[11] };
        __builtin_nontemporal_store(o0, ov + 0);
        __builtin_nontemporal_store(o1, ov + 1);
        __builtin_nontemporal_store(o2, ov + 2);
        f32x4 od = { di[0], di[1], di[2], di[3] };
        f32x4 os = { sw[0], sw[1], sw[2], sw[3] };
        f32x4 om = { mk[0], mk[1], mk[2], mk[3] };
        __builtin_nontemporal_store(od, (f32x4*)out_dist + t);
        __builtin_nontemporal_store(os, (f32x4*)out_sw   + t);
        __builtin_nontemporal_store(om, (f32x4*)out_mask + t);
    } else {
        for (int e = e0; e < n_edges; ++e) {
            float4 s = packed[esrc[e]], d = packed[edst[e]];
            float v0, v1, v2, di, sw, mk;
            edge_math(d.x - s.x, d.y - s.y, d.z - s.z,
                      shifts[3 * (size_t)e], shifts[3 * (size_t)e + 1],
                      shifts[3 * (size_t)e + 2], c, v0, v1, v2, di, sw, mk);
            out_vec[3 * (size_t)e]     = v0;
            out_vec[3 * (size_t)e + 1] = v1;
            out_vec[3 * (size_t)e + 2] = v2;
            out_dist[e] = di;
            out_sw[e]   = sw;
            out_mask[e] = mk;
        }
    }
}

// ---- fallback (ws too small): 12B struct gathers straight from coords ----
struct F3 { float x, y, z; };

__global__ __launch_bounds__(256) void GraphProcessor_fallback_kernel(
    const float* __restrict__ coords,
    const int*   __restrict__ esrc,
    const int*   __restrict__ edst,
    const float* __restrict__ shifts,
    const float* __restrict__ cells,
    float* __restrict__ out_vec,
    float* __restrict__ out_dist,
    float* __restrict__ out_sw,
    float* __restrict__ out_mask,
    int n_quads, int n_edges)
{
#pragma clang fp contract(off)
    int t = blockIdx.x * blockDim.x + threadIdx.x;
    if (t >= n_quads) return;

    float c[9];
#pragma unroll
    for (int i = 0; i < 9; ++i) c[i] = cells[i];

    const F3* nodes = (const F3*)coords;
    const int e0 = 4 * t;

    if (e0 + 3 < n_edges) {
        i32x4 ss = __builtin_nontemporal_load((const i32x4*)esrc + t);
        i32x4 dd = __builtin_nontemporal_load((const i32x4*)edst + t);
        const f32x4* shp = (const f32x4*)(shifts + 12 * (size_t)t);
        f32x4 h0 = __builtin_nontemporal_load(shp + 0);
        f32x4 h1 = __builtin_nontemporal_load(shp + 1);
        f32x4 h2 = __builtin_nontemporal_load(shp + 2);

        F3 s0 = nodes[ss.x], s1 = nodes[ss.y], s2 = nodes[ss.z], s3 = nodes[ss.w];
        F3 d0 = nodes[dd.x], d1 = nodes[dd.y], d2 = nodes[dd.z], d3 = nodes[dd.w];

        float v[12], di[4], sw[4], mk[4];
        edge_math(d0.x - s0.x, d0.y - s0.y, d0.z - s0.z, h0.x, h0.y, h0.z, c, v[0], v[1],  v[2],  di[0], sw[0], mk[0]);
        edge_math(d1.x - s1.x, d1.y - s1.y, d1.z - s1.z, h0.w, h1.x, h1.y, c, v[3], v[4],  v[5],  di[1], sw[1], mk[1]);
        edge_math(d2.x - s2.x, d2.y - s2.y, d2.z - s2.z, h1.z, h1.w, h2.x, c, v[6], v[7],  v[8],  di[2], sw[2], mk[2]);
        edge_math(d3.x - s3.x, d3.y - s3.y, d3.z - s3.z, h2.y, h2.z, h2.w, c, v[9], v[10], v[11], di[3], sw[3], mk[3]);

        f32x4* ov = (f32x4*)(out_vec + 12 * (size_t)t);
        f32x4 o0 = { v[0], v[1], v[2],  v[3]  };
        f32x4 o1 = { v[4], v[5], v[6],  v[7]  };
        f32x4 o2 = { v[8], v[9], v[10], v[11] };
        __builtin_nontemporal_store(o0, ov + 0);
        __builtin_nontemporal_store(o1, ov + 1);
        __builtin_nontemporal_store(o2, ov + 2);
        f32x4 od = { di[0], di[1], di[2], di[3] };
        f32x4 os = { sw[0], sw[1], sw[2], sw[3] };
        f32x4 om = { mk[0], mk[1], mk[2], mk[3] };
        __builtin_nontemporal_store(od, (f32x4*)out_dist + t);
        __builtin_nontemporal_store(os, (f32x4*)out_sw   + t);
        __builtin_nontemporal_store(om, (f32x4*)out_mask + t);
    } else {
        for (int e = e0; e < n_edges; ++e) {
            F3 s = nodes[esrc[e]], d = nodes[edst[e]];
            float v0, v1, v2, di, sw, mk;
            edge_math(d.x - s.x, d.y - s.y, d.z - s.z,
                      shifts[3 * (size_t)e], shifts[3 * (size_t)e + 1],
                      shifts[3 * (size_t)e + 2], c, v0, v1, v2, di, sw, mk);
            out_vec[3 * (size_t)e]     = v0;
            out_vec[3 * (size_t)e + 1] = v1;
            out_vec[3 * (size_t)e + 2] = v2;
            out_dist[e] = di;
            out_sw[e]   = sw;
            out_mask[e] = mk;
        }
    }
}

extern "C" void kernel_launch(void* const* d_in, const int* in_sizes, int n_in,
                              void* d_out, int out_size, void* d_ws, size_t ws_size,
                              hipStream_t stream) {
    const float* coords = (const float*)d_in[0];
    const int*   esrc   = (const int*)d_in[1];
    const int*   edst   = (const int*)d_in[2];
    const float* shifts = (const float*)d_in[3];
    const float* cells  = (const float*)d_in[4];

    const int N = in_sizes[0] / 3;  // n_nodes
    const int E = in_sizes[1];      // n_edges

    float* out      = (float*)d_out;
    float* out_vec  = out;                     // [E,3]
    float* out_dist = out + 3 * (size_t)E;     // [E]
    float* out_sw   = out_dist + E;            // [E]
    float* out_mask = out_sw + E;              // [E]

    const int n_quads = (E + 3) / 4;
    dim3 block(256);
    dim3 grid((n_quads + 255) / 256);

    if (ws_size >= (size_t)N * sizeof(float4)) {
        float4* packed = (float4*)d_ws;
        pack_coords_kernel<<<(N + 255) / 256, 256, 0, stream>>>(coords, packed, N);
        GraphProcessor_64012192579962_kernel<<<grid, block, 0, stream>>>(
            packed, esrc, edst, shifts, cells,
            out_vec, out_dist, out_sw, out_mask, n_quads, E);
    } else {
        GraphProcessor_fallback_kernel<<<grid, block, 0, stream>>>(
            coords, esrc, edst, shifts, cells,
            out_vec, out_dist, out_sw, out_mask, n_quads, E);
    }
}

// Round 3
// 169.583 us; speedup vs baseline: 1.0088x; 1.0088x over previous
//
#include <hip/hip_runtime.h>

// All tensors float32. Output = concat(vec[3E], dist[E], switch[E], mask[E]).
//
// R1 post-mortem: 71us, HBM 20%, VALU 8% -> bound by divergent-gather lane
// throughput (6 scalar dword gathers/edge, 12B payload straddling lines).
// R2: pack coords into float4[N] in d_ws (prepass) so each node gather is a
// single 16B-aligned dwordx4 (one line, one instr).
// R3/R4: nt loads on streaming inputs + nt stores on all outputs.
// R5 post-mortem of R4 (65us, 2.4TB/s=30%, VALU 8.8%, FETCH 48MB, WRITE 107MB):
//   - FETCH < 64MB ideal -> gathers are L2/L3-served, no HBM over-fetch. Good.
//   - WRITE is 1.4x the 76.8MB ideal: the out_vec nt stores are lane-strided
//     48B, so each nt store instruction only partially covers each 64B HBM
//     granule and early eviction defeats merging -> ~1.8x amplification on
//     the 38.4MB vec array (= the +30MB). dist/sw/mask nt stores are
//     lane-contiguous (full lines) -> innocent.
// R5 fix: out_vec goes back to plain cached stores (L2 merges stride-48 into
// full lines; R1 proved no amplification on the cached path). Keep nt on
// dist/sw/mask stores and on all streaming loads. Arithmetic unchanged
// (must stay bit-exact: the d<5 mask is a cliff; fp contract OFF, numpy op
// order, OCML sqrtf).

typedef float f32x4 __attribute__((ext_vector_type(4)));
typedef int   i32x4 __attribute__((ext_vector_type(4)));

__device__ __forceinline__ void edge_math(
    float dx0, float dx1, float dx2,
    float sh0, float sh1, float sh2, const float c[9],
    float& v0, float& v1, float& v2, float& dist, float& sw, float& mk)
{
#pragma clang fp contract(off)
    float m0 = sh0 * c[0]; m0 = m0 + sh1 * c[3]; m0 = m0 + sh2 * c[6];
    float m1 = sh0 * c[1]; m1 = m1 + sh1 * c[4]; m1 = m1 + sh2 * c[7];
    float m2 = sh0 * c[2]; m2 = m2 + sh1 * c[5]; m2 = m2 + sh2 * c[8];
    v0 = dx0 + m0; v1 = dx1 + m1; v2 = dx2 + m2;
    float q = v0 * v0; q = q + v1 * v1; q = q + v2 * v2;
    dist = sqrtf(q);
    bool m = dist < 5.0f;
    float cv = cosf(dist * 0.62831853f);   // f32(pi/5)
    sw = m ? (0.5f * cv + 0.5f) : 0.0f;
    mk = m ? 1.0f : 0.0f;
}

// ---- prepass: coords[N,3] -> packed float4[N] in ws ----
// packed table is the one thing we WANT in L2 -> regular (caching) stores.
__global__ __launch_bounds__(256) void pack_coords_kernel(
    const float* __restrict__ coords, float4* __restrict__ packed, int n_nodes)
{
    int i = blockIdx.x * blockDim.x + threadIdx.x;
    if (i >= n_nodes) return;
    const float* p = coords + 3 * (size_t)i;
    packed[i] = make_float4(p[0], p[1], p[2], 0.0f);
}

// ---- main kernel, packed-float4 gather path, nt streaming ----
__global__ __launch_bounds__(256) void GraphProcessor_64012192579962_kernel(
    const float4* __restrict__ packed,  // [N] xyz_
    const int*   __restrict__ esrc,     // [E]
    const int*   __restrict__ edst,     // [E]
    const float* __restrict__ shifts,   // [E,3]
    const float* __restrict__ cells,    // [9]
    float* __restrict__ out_vec,        // [E,3]
    float* __restrict__ out_dist,       // [E]
    float* __restrict__ out_sw,         // [E]
    float* __restrict__ out_mask,       // [E]
    int n_quads, int n_edges)
{
#pragma clang fp contract(off)
    int t = blockIdx.x * blockDim.x + threadIdx.x;
    if (t >= n_quads) return;

    float c[9];
#pragma unroll
    for (int i = 0; i < 9; ++i) c[i] = cells[i];   // uniform -> scalar loads

    const int e0 = 4 * t;

    if (e0 + 3 < n_edges) {
        // streaming, read-once -> nontemporal (don't evict the coord table)
        i32x4 ss = __builtin_nontemporal_load((const i32x4*)esrc + t);
        i32x4 dd = __builtin_nontemporal_load((const i32x4*)edst + t);
        const f32x4* shp = (const f32x4*)(shifts + 12 * (size_t)t);
        f32x4 h0 = __builtin_nontemporal_load(shp + 0);
        f32x4 h1 = __builtin_nontemporal_load(shp + 1);
        f32x4 h2 = __builtin_nontemporal_load(shp + 2);

        // issue all 8 gathers before any compute (max outstanding loads).
        // gathers stay normally cached: 1.6 MB table should be L2-resident.
        float4 s0 = packed[ss.x], s1 = packed[ss.y], s2 = packed[ss.z], s3 = packed[ss.w];
        float4 d0 = packed[dd.x], d1 = packed[dd.y], d2 = packed[dd.z], d3 = packed[dd.w];

        float v[12], di[4], sw[4], mk[4];
        edge_math(d0.x - s0.x, d0.y - s0.y, d0.z - s0.z, h0.x, h0.y, h0.z, c, v[0], v[1],  v[2],  di[0], sw[0], mk[0]);
        edge_math(d1.x - s1.x, d1.y - s1.y, d1.z - s1.z, h0.w, h1.x, h1.y, c, v[3], v[4],  v[5],  di[1], sw[1], mk[1]);
        edge_math(d2.x - s2.x, d2.y - s2.y, d2.z - s2.z, h1.z, h1.w, h2.x, c, v[6], v[7],  v[8],  di[2], sw[2], mk[2]);
        edge_math(d3.x - s3.x, d3.y - s3.y, d3.z - s3.z, h2.y, h2.z, h2.w, c, v[9], v[10], v[11], di[3], sw[3], mk[3]);

        // vec: lane-stride-48B pattern -> CACHED stores so L2 merges full
        // lines (nt here caused 1.4x write amplification, R5 post-mortem).
        float4* ov = (float4*)(out_vec + 12 * (size_t)t);
        ov[0] = make_float4(v[0], v[1], v[2],  v[3]);
        ov[1] = make_float4(v[4], v[5], v[6],  v[7]);
        ov[2] = make_float4(v[8], v[9], v[10], v[11]);

        // dist/sw/mask: lane-contiguous -> full lines per instr, keep nt.
        f32x4 od = { di[0], di[1], di[2], di[3] };
        f32x4 os = { sw[0], sw[1], sw[2], sw[3] };
        f32x4 om = { mk[0], mk[1], mk[2], mk[3] };
        __builtin_nontemporal_store(od, (f32x4*)out_dist + t);
        __builtin_nontemporal_store(os, (f32x4*)out_sw   + t);
        __builtin_nontemporal_store(om, (f32x4*)out_mask + t);
    } else {
        for (int e = e0; e < n_edges; ++e) {
            float4 s = packed[esrc[e]], d = packed[edst[e]];
            float v0, v1, v2, di, sw, mk;
            edge_math(d.x - s.x, d.y - s.y, d.z - s.z,
                      shifts[3 * (size_t)e], shifts[3 * (size_t)e + 1],
                      shifts[3 * (size_t)e + 2], c, v0, v1, v2, di, sw, mk);
            out_vec[3 * (size_t)e]     = v0;
            out_vec[3 * (size_t)e + 1] = v1;
            out_vec[3 * (size_t)e + 2] = v2;
            out_dist[e] = di;
            out_sw[e]   = sw;
            out_mask[e] = mk;
        }
    }
}

// ---- fallback (ws too small): 12B struct gathers straight from coords ----
struct F3 { float x, y, z; };

__global__ __launch_bounds__(256) void GraphProcessor_fallback_kernel(
    const float* __restrict__ coords,
    const int*   __restrict__ esrc,
    const int*   __restrict__ edst,
    const float* __restrict__ shifts,
    const float* __restrict__ cells,
    float* __restrict__ out_vec,
    float* __restrict__ out_dist,
    float* __restrict__ out_sw,
    float* __restrict__ out_mask,
    int n_quads, int n_edges)
{
#pragma clang fp contract(off)
    int t = blockIdx.x * blockDim.x + threadIdx.x;
    if (t >= n_quads) return;

    float c[9];
#pragma unroll
    for (int i = 0; i < 9; ++i) c[i] = cells[i];

    const F3* nodes = (const F3*)coords;
    const int e0 = 4 * t;

    if (e0 + 3 < n_edges) {
        i32x4 ss = __builtin_nontemporal_load((const i32x4*)esrc + t);
        i32x4 dd = __builtin_nontemporal_load((const i32x4*)edst + t);
        const f32x4* shp = (const f32x4*)(shifts + 12 * (size_t)t);
        f32x4 h0 = __builtin_nontemporal_load(shp + 0);
        f32x4 h1 = __builtin_nontemporal_load(shp + 1);
        f32x4 h2 = __builtin_nontemporal_load(shp + 2);

        F3 s0 = nodes[ss.x], s1 = nodes[ss.y], s2 = nodes[ss.z], s3 = nodes[ss.w];
        F3 d0 = nodes[dd.x], d1 = nodes[dd.y], d2 = nodes[dd.z], d3 = nodes[dd.w];

        float v[12], di[4], sw[4], mk[4];
        edge_math(d0.x - s0.x, d0.y - s0.y, d0.z - s0.z, h0.x, h0.y, h0.z, c, v[0], v[1],  v[2],  di[0], sw[0], mk[0]);
        edge_math(d1.x - s1.x, d1.y - s1.y, d1.z - s1.z, h0.w, h1.x, h1.y, c, v[3], v[4],  v[5],  di[1], sw[1], mk[1]);
        edge_math(d2.x - s2.x, d2.y - s2.y, d2.z - s2.z, h1.z, h1.w, h2.x, c, v[6], v[7],  v[8],  di[2], sw[2], mk[2]);
        edge_math(d3.x - s3.x, d3.y - s3.y, d3.z - s3.z, h2.y, h2.z, h2.w, c, v[9], v[10], v[11], di[3], sw[3], mk[3]);

        float4* ov = (float4*)(out_vec + 12 * (size_t)t);
        ov[0] = make_float4(v[0], v[1], v[2],  v[3]);
        ov[1] = make_float4(v[4], v[5], v[6],  v[7]);
        ov[2] = make_float4(v[8], v[9], v[10], v[11]);

        f32x4 od = { di[0], di[1], di[2], di[3] };
        f32x4 os = { sw[0], sw[1], sw[2], sw[3] };
        f32x4 om = { mk[0], mk[1], mk[2], mk[3] };
        __builtin_nontemporal_store(od, (f32x4*)out_dist + t);
        __builtin_nontemporal_store(os, (f32x4*)out_sw   + t);
        __builtin_nontemporal_store(om, (f32x4*)out_mask + t);
    } else {
        for (int e = e0; e < n_edges; ++e) {
            F3 s = nodes[esrc[e]], d = nodes[edst[e]];
            float v0, v1, v2, di, sw, mk;
            edge_math(d.x - s.x, d.y - s.y, d.z - s.z,
                      shifts[3 * (size_t)e], shifts[3 * (size_t)e + 1],
                      shifts[3 * (size_t)e + 2], c, v0, v1, v2, di, sw, mk);
            out_vec[3 * (size_t)e]     = v0;
            out_vec[3 * (size_t)e + 1] = v1;
            out_vec[3 * (size_t)e + 2] = v2;
            out_dist[e] = di;
            out_sw[e]   = sw;
            out_mask[e] = mk;
        }
    }
}

extern "C" void kernel_launch(void* const* d_in, const int* in_sizes, int n_in,
                              void* d_out, int out_size, void* d_ws, size_t ws_size,
                              hipStream_t stream) {
    const float* coords = (const float*)d_in[0];
    const int*   esrc   = (const int*)d_in[1];
    const int*   edst   = (const int*)d_in[2];
    const float* shifts = (const float*)d_in[3];
    const float* cells  = (const float*)d_in[4];

    const int N = in_sizes[0] / 3;  // n_nodes
    const int E = in_sizes[1];      // n_edges

    float* out      = (float*)d_out;
    float* out_vec  = out;                     // [E,3]
    float* out_dist = out + 3 * (size_t)E;     // [E]
    float* out_sw   = out_dist + E;            // [E]
    float* out_mask = out_sw + E;              // [E]

    const int n_quads = (E + 3) / 4;
    dim3 block(256);
    dim3 grid((n_quads + 255) / 256);

    if (ws_size >= (size_t)N * sizeof(float4)) {
        float4* packed = (float4*)d_ws;
        pack_coords_kernel<<<(N + 255) / 256, 256, 0, stream>>>(coords, packed, N);
        GraphProcessor_64012192579962_kernel<<<grid, block, 0, stream>>>(
            packed, esrc, edst, shifts, cells,
            out_vec, out_dist, out_sw, out_mask, n_quads, E);
    } else {
        GraphProcessor_fallback_kernel<<<grid, block, 0, stream>>>(
            coords, esrc, edst, shifts, cells,
            out_vec, out_dist, out_sw, out_mask, n_quads, E);
    }
}